// Round 20
// baseline (199.916 us; speedup 1.0000x reference)
//
#include <hip/hip_runtime.h>
#include <hip/hip_bf16.h>

#define D 128        // d_in = d_out
#define NCOLS 256    // HEADS * D
#define NPB 256      // nodes per bucket (pow2: bucket = dst >> 8)
#define CAP 12288    // per-bucket bin capacity (mean ~4096, 3x margin)
#define P1CHUNK 4096 // edges per bin block

using f16x8 = __attribute__((ext_vector_type(8))) _Float16;
using f16x2 = __attribute__((ext_vector_type(2))) _Float16;
using f32x4 = __attribute__((ext_vector_type(4))) float;

__device__ inline int edge_val(const void* ei, int is32, long long idx) {
    if (is32) return ((const int*)ei)[idx];
    return (int)(((const long long*)ei)[idx]);
}

// ---------------- attprep (blocks 0..33) + detect/zero (block 34) -----------
__global__ __launch_bounds__(256) void attprep_kernel(
    const float* __restrict__ W1, const float* __restrict__ as1,
    const float* __restrict__ ad1, float* __restrict__ v_s1,
    float* __restrict__ v_d1, _Float16* __restrict__ wT1,
    const float* __restrict__ W2, const float* __restrict__ as2,
    const float* __restrict__ ad2, float* __restrict__ v_s2,
    float* __restrict__ v_d2, _Float16* __restrict__ wT2,
    const void* __restrict__ ei, int* __restrict__ flag, int* __restrict__ gcnt) {
    int tid = threadIdx.x;
    if (blockIdx.x == 34) {                      // detect + gcnt zero
        gcnt[tid] = 0;
        if (tid == 0) *flag = 0;
        __syncthreads();
        const unsigned* u = (const unsigned*)ei;
        if (u[2 * tid + 1] != 0) *flag = 1;      // 1 => data is int32
        return;
    }
    int layer = blockIdx.x >= 17;
    int bx = blockIdx.x - (layer ? 17 : 0);
    const float* W = layer ? W2 : W1;
    const float* att_s = layer ? as2 : as1;
    const float* att_d = layer ? ad2 : ad1;
    float* v_s = layer ? v_s2 : v_s1;
    float* v_d = layer ? v_d2 : v_d1;
    _Float16* wT = layer ? wT2 : wT1;
    if (bx == 16) {
        int h = tid >> 7, d = tid & 127;
        const float* wrow = W + d * NCOLS + h * D;
        const float* as = att_s + h * D;
        const float* ad = att_d + h * D;
        float ss = 0.f, sd = 0.f;
        for (int i = 0; i < D; i += 4) {
            float4 wv = *reinterpret_cast<const float4*>(wrow + i);
            float4 av = *reinterpret_cast<const float4*>(as + i);
            float4 dv = *reinterpret_cast<const float4*>(ad + i);
            ss += wv.x * av.x + wv.y * av.y + wv.z * av.z + wv.w * av.w;
            sd += wv.x * dv.x + wv.y * dv.y + wv.z * dv.z + wv.w * dv.w;
        }
        v_s[tid] = ss;
        v_d[tid] = sd;
    } else {
        int base = bx * 2048 + tid * 8;   // kk fixed, i..i+7
#pragma unroll
        for (int t = 0; t < 8; t += 4) {
            int f = base + t;
            int kk = f >> 7, i = f & 127;
            int h = kk >> 7, d = kk & 127;
            float4 wv = *reinterpret_cast<const float4*>(W + d * NCOLS + h * D + i);
            wT[(size_t)(i + 0) * NCOLS + kk] = (_Float16)(0.5f * wv.x);
            wT[(size_t)(i + 1) * NCOLS + kk] = (_Float16)(0.5f * wv.y);
            wT[(size_t)(i + 2) * NCOLS + kk] = (_Float16)(0.5f * wv.z);
            wT[(size_t)(i + 3) * NCOLS + kk] = (_Float16)(0.5f * wv.w);
        }
    }
}

// ---------------- binprep: blocks [0,NBB) bin edges; rest do prep_x ---------
__global__ __launch_bounds__(256) void binprep_kernel(
    const void* __restrict__ ei, const int* __restrict__ flag,
    unsigned* __restrict__ bins, int* __restrict__ gcnt, int E, int nbuck,
    const float* __restrict__ x, const float* __restrict__ v_s,
    const float* __restrict__ v_d, _Float16* __restrict__ xh,
    float* __restrict__ a_s, float* __restrict__ a_d, int n, int NBB) {
    __shared__ int cnt[256], cur[256], gb[256];
    int tid = threadIdx.x;
    if ((int)blockIdx.x < NBB) {
        int base = blockIdx.x * P1CHUNK;
        int m = min(P1CHUNK, E - base);
        int is32 = *flag;
        cnt[tid] = 0; cur[tid] = 0;
        __syncthreads();
        for (int i = tid; i < m; i += 256) {
            int dst = edge_val(ei, is32, (long long)E + base + i);
            atomicAdd(&cnt[dst >> 8], 1);
        }
        __syncthreads();
        if (tid < nbuck && cnt[tid] > 0) gb[tid] = atomicAdd(&gcnt[tid], cnt[tid]);
        else gb[tid] = 0;
        __syncthreads();
        for (int i = tid; i < m; i += 256) {
            int src = edge_val(ei, is32, base + i);
            int dst = edge_val(ei, is32, (long long)E + base + i);
            int b = dst >> 8;
            int pos = gb[b] + atomicAdd(&cur[b], 1);
            if (pos < CAP)
                bins[(size_t)b * CAP + pos] = ((unsigned)(dst & 255) << 16) | (unsigned)src;
        }
        return;
    }
    // ---- prep_x ----
    int lane = tid & 63;
    int node = ((int)blockIdx.x - NBB) * 4 + (tid >> 6);
    if (node >= n) return;
    float2 xv = *reinterpret_cast<const float2*>(x + (size_t)node * D + 2 * lane);
    f16x2 hx = {(_Float16)xv.x, (_Float16)xv.y};
    *reinterpret_cast<f16x2*>(xh + (size_t)node * D + 2 * lane) = hx;
    float2 vs0 = *reinterpret_cast<const float2*>(v_s + 2 * lane);
    float2 vs1 = *reinterpret_cast<const float2*>(v_s + D + 2 * lane);
    float2 vd0 = *reinterpret_cast<const float2*>(v_d + 2 * lane);
    float2 vd1 = *reinterpret_cast<const float2*>(v_d + D + 2 * lane);
    float s0 = xv.x * vs0.x + xv.y * vs0.y;
    float s1 = xv.x * vs1.x + xv.y * vs1.y;
    float d0 = xv.x * vd0.x + xv.y * vd0.y;
    float d1 = xv.x * vd1.x + xv.y * vd1.y;
#pragma unroll
    for (int off = 1; off < 64; off <<= 1) {
        s0 += __shfl_xor(s0, off, 64);
        s1 += __shfl_xor(s1, off, 64);
        d0 += __shfl_xor(d0, off, 64);
        d1 += __shfl_xor(d1, off, 64);
    }
    if (lane == 0) {
        *reinterpret_cast<float2*>(a_s + (size_t)node * 2) = make_float2(s0, s1);
        *reinterpret_cast<float2*>(a_d + (size_t)node * 2) = make_float2(d0, d1);
    }
}

// ---------------- per-bucket local CSR build (r16 version, no perm) ---------
__global__ __launch_bounds__(256) void build_kernel(
    const unsigned* __restrict__ bins, const int* __restrict__ gcnt,
    int* __restrict__ row_ptr, int* __restrict__ csr_src, int n, int nbuck) {
    __shared__ unsigned items[CAP];
    __shared__ int deg[256], sc[256], cur[256], pref[256];
    int b = blockIdx.x, tid = threadIdx.x;
    int node0 = b * NPB;
    int nn = min(n - node0, NPB);
    int cnt = min(gcnt[b], CAP);
    int t = 0;
    if (tid < b) {
        int lo = tid * NPB, hi = min(n, lo + NPB);
        t = min(gcnt[tid], CAP) + (hi - lo);
    }
    pref[tid] = t;
    const unsigned* src = bins + (size_t)b * CAP;
    for (int i = tid; i < cnt; i += 256) items[i] = src[i];
    deg[tid] = (tid < nn) ? 1 : 0;             // self loop
    __syncthreads();
#pragma unroll
    for (int off = 128; off >= 1; off >>= 1) {
        if (tid < off) pref[tid] += pref[tid + off];
        __syncthreads();
    }
    int gb = pref[0];
    for (int i = tid; i < cnt; i += 256) atomicAdd(&deg[(items[i] >> 16) & 255], 1);
    __syncthreads();
    int d = deg[tid];
    sc[tid] = d;
    __syncthreads();
#pragma unroll
    for (int off = 1; off < 256; off <<= 1) {
        int u = (tid >= off) ? sc[tid - off] : 0;
        __syncthreads();
        sc[tid] += u;
        __syncthreads();
    }
    int incl = sc[tid];
    int excl = incl - d;
    if (tid < nn) row_ptr[node0 + tid + 1] = gb + incl;
    if (b == 0 && tid == 0) row_ptr[0] = 0;
    cur[tid] = excl + ((tid < nn) ? 1 : 0);    // reserve slot 0 for self loop
    if (tid < nn) csr_src[gb + excl] = node0 + tid;
    __syncthreads();
    for (int i = tid; i < cnt; i += 256) {
        unsigned it = items[i];
        int p = atomicAdd(&cur[(it >> 16) & 255], 1);
        csr_src[gb + p] = (int)(it & 0xFFFFu);
    }
}

// ---------------- fused: aggregate 16 nodes (dual-gather) -> LDS -> MFMA ----
// r16 structure; phase 1 processes each wave's 4 nodes as 2 CONCURRENT pairs:
// per iteration the loads for node A and node B are both issued before either
// FMA block -> 2x memory-level parallelism per wave (the r16->r15 BW gap).
__global__ __launch_bounds__(256) void agg_mfma_kernel(
    const _Float16* __restrict__ xh, const float* __restrict__ a_s,
    const float* __restrict__ a_d, const int* __restrict__ row_ptr,
    const int* __restrict__ csr_src, const _Float16* __restrict__ wT,
    const float* __restrict__ bias, const float* __restrict__ vs_next,
    const float* __restrict__ vd_next, float* __restrict__ as_next,
    float* __restrict__ ad_next, float* __restrict__ outf,
    _Float16* __restrict__ outh, int n) {
    __shared__ __align__(16) _Float16 Alds[8 * 512];   // 8 KB
    __shared__ float part[4][16][4];                   // 1 KB
    int tid = threadIdx.x;
    int wave = tid >> 6, lane = tid & 63;
    int m0 = blockIdx.x * 16;
    int sub = lane >> 4, cq = lane & 15;
    const _Float16* xb = xh + 8 * cq;

    // ---- phase 1: 2 pairs of concurrently-gathered nodes per wave ----
#pragma unroll 1
    for (int pair = 0; pair < 2; ++pair) {
        int nlA = wave * 4 + pair * 2;
        int nlB = nlA + 1;
        int nodeA = m0 + nlA, nodeB = m0 + nlB;
        bool okA = nodeA < n, okB = nodeB < n;
        if (!okA) break;
        int begA = row_ptr[nodeA], endA = row_ptr[nodeA + 1];
        int begB = 0, endB = 0;
        float2 adA = *reinterpret_cast<const float2*>(a_d + (size_t)nodeA * 2);
        float2 adB = make_float2(0.f, 0.f);
        if (okB) {
            begB = row_ptr[nodeB];
            endB = row_ptr[nodeB + 1];
            adB = *reinterpret_cast<const float2*>(a_d + (size_t)nodeB * 2);
        }
        float sA0 = 0.f, sA1 = 0.f, sB0 = 0.f, sB1 = 0.f;
        float aA0[8] = {}, aA1[8] = {}, aB0[8] = {}, aB1[8] = {};
        int cA = begA, cB = begB;
        while (cA < endA || cB < endB) {
            int cntA = min(64, endA - cA);
            int cntB = min(64, endB - cB);
            int jA = 0, jB = 0;
            unsigned ppA = 0, ppB = 0;
            if (cntA > 0 && lane < cntA) {
                jA = csr_src[cA + lane];
                float2 as2 = *reinterpret_cast<const float2*>(a_s + (size_t)jA * 2);
                float e0 = as2.x + adA.x; e0 = (e0 > 0.f) ? e0 : 0.2f * e0;
                float e1 = as2.y + adA.y; e1 = (e1 > 0.f) ? e1 : 0.2f * e1;
                f16x2 pq = {(_Float16)__expf(e0), (_Float16)__expf(e1)};
                ppA = __builtin_bit_cast(unsigned, pq);
                sA0 += (float)pq[0];
                sA1 += (float)pq[1];
            }
            if (cntB > 0 && lane < cntB) {
                jB = csr_src[cB + lane];
                float2 as2 = *reinterpret_cast<const float2*>(a_s + (size_t)jB * 2);
                float e0 = as2.x + adB.x; e0 = (e0 > 0.f) ? e0 : 0.2f * e0;
                float e1 = as2.y + adB.y; e1 = (e1 > 0.f) ? e1 : 0.2f * e1;
                f16x2 pq = {(_Float16)__expf(e0), (_Float16)__expf(e1)};
                ppB = __builtin_bit_cast(unsigned, pq);
                sB0 += (float)pq[0];
                sB1 += (float)pq[1];
            }
            int kmax = max(cntA, cntB);
#pragma unroll 2
            for (int k = 0; k < kmax; k += 4) {
                int idx = k + sub;
                bool doA = k < cntA, doB = k < cntB;
                unsigned puA = 0, puB = 0;
                f16x8 hvA = {}, hvB = {};
                if (doA) {
                    puA = (unsigned)__shfl((int)ppA, idx, 64);
                    int jj = __shfl(jA, idx, 64);
                    hvA = *reinterpret_cast<const f16x8*>(xb + (size_t)jj * D);
                }
                if (doB) {
                    puB = (unsigned)__shfl((int)ppB, idx, 64);
                    int jj = __shfl(jB, idx, 64);
                    hvB = *reinterpret_cast<const f16x8*>(xb + (size_t)jj * D);
                }
                if (doA) {
                    f16x2 pq = __builtin_bit_cast(f16x2, puA);
                    float p0 = (float)pq[0], p1 = (float)pq[1];
#pragma unroll
                    for (int i = 0; i < 8; ++i) {
                        float h = (float)hvA[i];
                        aA0[i] += p0 * h;
                        aA1[i] += p1 * h;
                    }
                }
                if (doB) {
                    f16x2 pq = __builtin_bit_cast(f16x2, puB);
                    float p0 = (float)pq[0], p1 = (float)pq[1];
#pragma unroll
                    for (int i = 0; i < 8; ++i) {
                        float h = (float)hvB[i];
                        aB0[i] += p0 * h;
                        aB1[i] += p1 * h;
                    }
                }
            }
            cA += 64;
            cB += 64;
        }
#pragma unroll
        for (int i = 0; i < 8; ++i) {
            aA0[i] += __shfl_xor(aA0[i], 16, 64);
            aA0[i] += __shfl_xor(aA0[i], 32, 64);
            aA1[i] += __shfl_xor(aA1[i], 16, 64);
            aA1[i] += __shfl_xor(aA1[i], 32, 64);
            aB0[i] += __shfl_xor(aB0[i], 16, 64);
            aB0[i] += __shfl_xor(aB0[i], 32, 64);
            aB1[i] += __shfl_xor(aB1[i], 16, 64);
            aB1[i] += __shfl_xor(aB1[i], 32, 64);
        }
#pragma unroll
        for (int off = 1; off < 64; off <<= 1) {
            sA0 += __shfl_xor(sA0, off, 64);
            sA1 += __shfl_xor(sA1, off, 64);
            sB0 += __shfl_xor(sB0, off, 64);
            sB1 += __shfl_xor(sB1, off, 64);
        }
        if (sub == 0) {
            int kt0 = cq >> 2, g0 = cq & 3;
            {
                float i0 = 1.f / sA0, i1 = 1.f / sA1;
                f16x8 o0, o1;
#pragma unroll
                for (int i = 0; i < 8; ++i) {
                    o0[i] = (_Float16)(aA0[i] * i0);
                    o1[i] = (_Float16)(aA1[i] * i1);
                }
                *reinterpret_cast<f16x8*>(Alds + kt0 * 512 + (g0 * 16 + nlA) * 8)       = o0;
                *reinterpret_cast<f16x8*>(Alds + (4 + kt0) * 512 + (g0 * 16 + nlA) * 8) = o1;
            }
            if (okB) {
                float i0 = 1.f / sB0, i1 = 1.f / sB1;
                f16x8 o0, o1;
#pragma unroll
                for (int i = 0; i < 8; ++i) {
                    o0[i] = (_Float16)(aB0[i] * i0);
                    o1[i] = (_Float16)(aB1[i] * i1);
                }
                *reinterpret_cast<f16x8*>(Alds + kt0 * 512 + (g0 * 16 + nlB) * 8)       = o0;
                *reinterpret_cast<f16x8*>(Alds + (4 + kt0) * 512 + (g0 * 16 + nlB) * 8) = o1;
            }
        }
    }
    __syncthreads();

    // ---- phase 2: MFMA, wave covers cols 32*wave .. 32*wave+31 ----
    int ml = lane & 15, g = lane >> 4;
    f32x4 accA = {}, accB = {};
    int nt0 = wave * 2, nt1 = wave * 2 + 1;
    const _Float16* b0 = wT + (size_t)(nt0 * 16 + ml) * NCOLS + 8 * g;
    const _Float16* b1 = wT + (size_t)(nt1 * 16 + ml) * NCOLS + 8 * g;
#pragma unroll
    for (int kt = 0; kt < 8; ++kt) {
        f16x8 av = *reinterpret_cast<const f16x8*>(Alds + kt * 512 + lane * 8);
        int ko = kt * 32;
        f16x8 bv0 = *reinterpret_cast<const f16x8*>(b0 + ko);
        f16x8 bv1 = *reinterpret_cast<const f16x8*>(b1 + ko);
        accA = __builtin_amdgcn_mfma_f32_16x16x32_f16(av, bv0, accA, 0, 0, 0);
        accB = __builtin_amdgcn_mfma_f32_16x16x32_f16(av, bv1, accB, 0, 0, 0);
    }

    int col0 = nt0 * 16 + ml, col1 = nt1 * 16 + ml;
    float bA = bias[col0], bB = bias[col1];
    float vsA0 = 0.f, vsA1 = 0.f, vdA0 = 0.f, vdA1 = 0.f;
    float vsB0 = 0.f, vsB1 = 0.f, vdB0 = 0.f, vdB1 = 0.f;
    if (vs_next) {
        vsA0 = vs_next[col0]; vsA1 = vs_next[D + col0];
        vdA0 = vd_next[col0]; vdA1 = vd_next[D + col0];
        vsB0 = vs_next[col1]; vsB1 = vs_next[D + col1];
        vdB0 = vd_next[col1]; vdB1 = vd_next[D + col1];
    }

#pragma unroll
    for (int r = 0; r < 4; ++r) {
        int lrow = g * 4 + r;
        int orow = m0 + lrow;
        float vA = accA[r] + bA;
        float vB = accB[r] + bB;
        if (orow < n) {
            if (outf) {
                outf[(size_t)orow * D + col0] = vA;
                outf[(size_t)orow * D + col1] = vB;
            }
            if (outh) {
                outh[(size_t)orow * D + col0] = (_Float16)vA;
                outh[(size_t)orow * D + col1] = (_Float16)vB;
            }
        }
        if (vs_next) {
            float ps0 = vA * vsA0 + vB * vsB0;
            float ps1 = vA * vsA1 + vB * vsB1;
            float pd0 = vA * vdA0 + vB * vdB0;
            float pd1 = vA * vdA1 + vB * vdB1;
#pragma unroll
            for (int off = 1; off < 16; off <<= 1) {
                ps0 += __shfl_xor(ps0, off, 64);
                ps1 += __shfl_xor(ps1, off, 64);
                pd0 += __shfl_xor(pd0, off, 64);
                pd1 += __shfl_xor(pd1, off, 64);
            }
            if (ml == 0) {
                part[wave][lrow][0] = ps0;
                part[wave][lrow][1] = ps1;
                part[wave][lrow][2] = pd0;
                part[wave][lrow][3] = pd1;
            }
        }
    }
    if (vs_next) {
        __syncthreads();
        if (tid < 64) {
            int row = tid >> 2, q = tid & 3;
            int node = m0 + row;
            if (node < n) {
                float v = part[0][row][q] + part[1][row][q]
                        + part[2][row][q] + part[3][row][q];
                float* dstp = (q < 2) ? as_next : ad_next;
                dstp[(size_t)node * 2 + (q & 1)] = v;
            }
        }
    }
}

// ---------------- launch ----------------
extern "C" void kernel_launch(void* const* d_in, const int* in_sizes, int n_in,
                              void* d_out, int out_size, void* d_ws, size_t ws_size,
                              hipStream_t stream) {
    const float* x    = (const float*)d_in[0];
    const void*  ei   = d_in[1];
    const float* W1   = (const float*)d_in[2];
    const float* as1v = (const float*)d_in[3];
    const float* ad1v = (const float*)d_in[4];
    const float* b1   = (const float*)d_in[5];
    const float* W2   = (const float*)d_in[6];
    const float* as2v = (const float*)d_in[7];
    const float* ad2v = (const float*)d_in[8];
    const float* b2   = (const float*)d_in[9];
    float* out = (float*)d_out;

    const int N  = in_sizes[0] / D;
    const int E  = in_sizes[1] / 2;
    const int ET = E + N;
    const int NBUCK = (N + NPB - 1) / NPB;
    const int NBB = (E + P1CHUNK - 1) / P1CHUNK;

    char* w = (char*)d_ws;
    size_t off = 0;
    auto alloc = [&](size_t bytes) {
        void* p = w + off;
        off = (off + bytes + 15) & ~(size_t)15;
        return p;
    };
    int*      flag    = (int*)     alloc(16);
    int*      gcnt    = (int*)     alloc(256 * 4);
    unsigned* bins    = (unsigned*)alloc((size_t)NBUCK * CAP * 4);
    int*      row_ptr = (int*)     alloc((size_t)(N + 1) * 4);
    int*      csr_src = (int*)     alloc((size_t)ET * 4);
    float*    v_s1    = (float*)   alloc(NCOLS * 4);
    float*    v_d1    = (float*)   alloc(NCOLS * 4);
    _Float16* wT1     = (_Float16*)alloc((size_t)NCOLS * D * 2);
    float*    v_s2    = (float*)   alloc(NCOLS * 4);
    float*    v_d2    = (float*)   alloc(NCOLS * 4);
    _Float16* wT2     = (_Float16*)alloc((size_t)NCOLS * D * 2);
    float*    a_s1    = (float*)   alloc((size_t)N * 2 * 4);
    float*    a_d1    = (float*)   alloc((size_t)N * 2 * 4);
    float*    a_s2    = (float*)   alloc((size_t)N * 2 * 4);
    float*    a_d2    = (float*)   alloc((size_t)N * 2 * 4);
    _Float16* xh      = (_Float16*)alloc((size_t)N * D * 2);
    _Float16* xmh     = (_Float16*)alloc((size_t)N * D * 2);

    // 1) weight prep + detect/zero
    hipLaunchKernelGGL(attprep_kernel, dim3(35), dim3(256), 0, stream,
                       W1, as1v, ad1v, v_s1, v_d1, wT1,
                       W2, as2v, ad2v, v_s2, v_d2, wT2, ei, flag, gcnt);
    // 2) bin + prep_x
    hipLaunchKernelGGL(binprep_kernel, dim3(NBB + (N + 3) / 4), dim3(256), 0, stream,
                       ei, flag, bins, gcnt, E, NBUCK,
                       x, v_s1, v_d1, xh, a_s1, a_d1, N, NBB);
    // 3) CSR build
    hipLaunchKernelGGL(build_kernel, dim3(NBUCK), dim3(256), 0, stream,
                       bins, gcnt, row_ptr, csr_src, N, NBUCK);
    // 4) layer 1 fused (emits xmh + layer-2 a_s/a_d)
    hipLaunchKernelGGL(agg_mfma_kernel, dim3((N + 15) / 16), dim3(256), 0, stream,
                       xh, a_s1, a_d1, row_ptr, csr_src, wT1, b1,
                       v_s2, v_d2, a_s2, a_d2, (float*)nullptr, xmh, N);
    // 5) layer 2 fused (emits out)
    hipLaunchKernelGGL(agg_mfma_kernel, dim3((N + 15) / 16), dim3(256), 0, stream,
                       xmh, a_s2, a_d2, row_ptr, csr_src, wT2, b2,
                       (const float*)nullptr, (const float*)nullptr,
                       (float*)nullptr, (float*)nullptr, out, (_Float16*)nullptr, N);
}

// Round 21
// 178.673 us; speedup vs baseline: 1.1189x; 1.1189x over previous
//
#include <hip/hip_runtime.h>
#include <hip/hip_bf16.h>

#define D 128        // d_in = d_out
#define NCOLS 256    // HEADS * D
#define NPB 256      // nodes per bucket (pow2: bucket = dst >> 8)
#define CAP 12288    // per-bucket bin capacity (mean ~4096, 3x margin)
#define P1CHUNK 4096 // edges per bin block

using f16x8 = __attribute__((ext_vector_type(8))) _Float16;
using f16x2 = __attribute__((ext_vector_type(2))) _Float16;
using f32x4 = __attribute__((ext_vector_type(4))) float;

__device__ inline int edge_val(const void* ei, int is32, long long idx) {
    if (is32) return ((const int*)ei)[idx];
    return (int)(((const long long*)ei)[idx]);
}

// ---------------- attprep (blocks 0..33) + edge-dtype detect (block 34) -----
__global__ __launch_bounds__(256) void attprep_kernel(
    const float* __restrict__ W1, const float* __restrict__ as1,
    const float* __restrict__ ad1, float* __restrict__ v_s1,
    float* __restrict__ v_d1, _Float16* __restrict__ wT1,
    const float* __restrict__ W2, const float* __restrict__ as2,
    const float* __restrict__ ad2, float* __restrict__ v_s2,
    float* __restrict__ v_d2, _Float16* __restrict__ wT2,
    const void* __restrict__ ei, int* __restrict__ flag, int* __restrict__ gcnt) {
    int tid = threadIdx.x;
    if (blockIdx.x == 34) {                      // detect + gcnt zero
        gcnt[tid] = 0;
        if (tid == 0) *flag = 0;
        __syncthreads();
        const unsigned* u = (const unsigned*)ei;
        if (u[2 * tid + 1] != 0) *flag = 1;      // 1 => data is int32
        return;
    }
    int layer = blockIdx.x >= 17;
    int bx = blockIdx.x - (layer ? 17 : 0);
    const float* W = layer ? W2 : W1;
    const float* att_s = layer ? as2 : as1;
    const float* att_d = layer ? ad2 : ad1;
    float* v_s = layer ? v_s2 : v_s1;
    float* v_d = layer ? v_d2 : v_d1;
    _Float16* wT = layer ? wT2 : wT1;
    if (bx == 16) {
        int h = tid >> 7, d = tid & 127;
        const float* wrow = W + d * NCOLS + h * D;
        const float* as = att_s + h * D;
        const float* ad = att_d + h * D;
        float ss = 0.f, sd = 0.f;
        for (int i = 0; i < D; i += 4) {
            float4 wv = *reinterpret_cast<const float4*>(wrow + i);
            float4 av = *reinterpret_cast<const float4*>(as + i);
            float4 dv = *reinterpret_cast<const float4*>(ad + i);
            ss += wv.x * av.x + wv.y * av.y + wv.z * av.z + wv.w * av.w;
            sd += wv.x * dv.x + wv.y * dv.y + wv.z * dv.z + wv.w * dv.w;
        }
        v_s[tid] = ss;
        v_d[tid] = sd;
    } else {
        int base = bx * 2048 + tid * 8;   // kk fixed, i..i+7
#pragma unroll
        for (int t = 0; t < 8; t += 4) {
            int f = base + t;
            int kk = f >> 7, i = f & 127;
            int h = kk >> 7, d = kk & 127;
            float4 wv = *reinterpret_cast<const float4*>(W + d * NCOLS + h * D + i);
            wT[(size_t)(i + 0) * NCOLS + kk] = (_Float16)(0.5f * wv.x);
            wT[(size_t)(i + 1) * NCOLS + kk] = (_Float16)(0.5f * wv.y);
            wT[(size_t)(i + 2) * NCOLS + kk] = (_Float16)(0.5f * wv.z);
            wT[(size_t)(i + 3) * NCOLS + kk] = (_Float16)(0.5f * wv.w);
        }
    }
}

// ---------------- binprep: blocks [0,NBB) bin edges; rest do prep_x ---------
__global__ __launch_bounds__(256) void binprep_kernel(
    const void* __restrict__ ei, const int* __restrict__ flag,
    unsigned* __restrict__ bins, int* __restrict__ gcnt, int E, int nbuck,
    const float* __restrict__ x, const float* __restrict__ v_s,
    const float* __restrict__ v_d, _Float16* __restrict__ xh,
    float* __restrict__ a_s, float* __restrict__ a_d, int n, int NBB) {
    __shared__ int cnt[256], cur[256], gb[256];
    int tid = threadIdx.x;
    if ((int)blockIdx.x < NBB) {
        // ---- bin: two-pass, no scratch ----
        int base = blockIdx.x * P1CHUNK;
        int m = min(P1CHUNK, E - base);
        int is32 = *flag;
        cnt[tid] = 0; cur[tid] = 0;
        __syncthreads();
        for (int i = tid; i < m; i += 256) {
            int dst = edge_val(ei, is32, (long long)E + base + i);
            atomicAdd(&cnt[dst >> 8], 1);
        }
        __syncthreads();
        if (tid < nbuck && cnt[tid] > 0) gb[tid] = atomicAdd(&gcnt[tid], cnt[tid]);
        else gb[tid] = 0;
        __syncthreads();
        for (int i = tid; i < m; i += 256) {
            int src = edge_val(ei, is32, base + i);
            int dst = edge_val(ei, is32, (long long)E + base + i);
            int b = dst >> 8;
            int pos = gb[b] + atomicAdd(&cur[b], 1);
            if (pos < CAP)
                bins[(size_t)b * CAP + pos] = ((unsigned)(dst & 255) << 16) | (unsigned)src;
        }
        return;
    }
    // ---- prep_x: xh = fp16(x) + a_s/a_d = x . v ----
    int lane = tid & 63;
    int node = ((int)blockIdx.x - NBB) * 4 + (tid >> 6);
    if (node >= n) return;
    float2 xv = *reinterpret_cast<const float2*>(x + (size_t)node * D + 2 * lane);
    f16x2 hx = {(_Float16)xv.x, (_Float16)xv.y};
    *reinterpret_cast<f16x2*>(xh + (size_t)node * D + 2 * lane) = hx;
    float2 vs0 = *reinterpret_cast<const float2*>(v_s + 2 * lane);
    float2 vs1 = *reinterpret_cast<const float2*>(v_s + D + 2 * lane);
    float2 vd0 = *reinterpret_cast<const float2*>(v_d + 2 * lane);
    float2 vd1 = *reinterpret_cast<const float2*>(v_d + D + 2 * lane);
    float s0 = xv.x * vs0.x + xv.y * vs0.y;
    float s1 = xv.x * vs1.x + xv.y * vs1.y;
    float d0 = xv.x * vd0.x + xv.y * vd0.y;
    float d1 = xv.x * vd1.x + xv.y * vd1.y;
#pragma unroll
    for (int off = 1; off < 64; off <<= 1) {
        s0 += __shfl_xor(s0, off, 64);
        s1 += __shfl_xor(s1, off, 64);
        d0 += __shfl_xor(d0, off, 64);
        d1 += __shfl_xor(d1, off, 64);
    }
    if (lane == 0) {
        *reinterpret_cast<float2*>(a_s + (size_t)node * 2) = make_float2(s0, s1);
        *reinterpret_cast<float2*>(a_d + (size_t)node * 2) = make_float2(d0, d1);
    }
}

// ---------------- per-bucket local CSR build (self-computed base) -----------
__global__ __launch_bounds__(256) void build_kernel(
    const unsigned* __restrict__ bins, const int* __restrict__ gcnt,
    int* __restrict__ row_ptr, int* __restrict__ csr_src, int n, int nbuck) {
    __shared__ unsigned items[CAP];
    __shared__ int deg[256], sc[256], cur[256], pref[256];
    int b = blockIdx.x, tid = threadIdx.x;
    int node0 = b * NPB;
    int nn = min(n - node0, NPB);
    int cnt = min(gcnt[b], CAP);
    int t = 0;
    if (tid < b) {
        int lo = tid * NPB, hi = min(n, lo + NPB);
        t = min(gcnt[tid], CAP) + (hi - lo);
    }
    pref[tid] = t;
    const unsigned* src = bins + (size_t)b * CAP;
    for (int i = tid; i < cnt; i += 256) items[i] = src[i];
    deg[tid] = (tid < nn) ? 1 : 0;             // self loop
    __syncthreads();
#pragma unroll
    for (int off = 128; off >= 1; off >>= 1) {
        if (tid < off) pref[tid] += pref[tid + off];
        __syncthreads();
    }
    int gb = pref[0];
    for (int i = tid; i < cnt; i += 256) atomicAdd(&deg[(items[i] >> 16) & 255], 1);
    __syncthreads();
    int d = deg[tid];
    sc[tid] = d;
    __syncthreads();
#pragma unroll
    for (int off = 1; off < 256; off <<= 1) {
        int u = (tid >= off) ? sc[tid - off] : 0;
        __syncthreads();
        sc[tid] += u;
        __syncthreads();
    }
    int incl = sc[tid];
    int excl = incl - d;
    if (tid < nn) row_ptr[node0 + tid + 1] = gb + incl;
    if (b == 0 && tid == 0) row_ptr[0] = 0;
    cur[tid] = excl + ((tid < nn) ? 1 : 0);    // reserve slot 0 for self loop
    if (tid < nn) csr_src[gb + excl] = node0 + tid;
    __syncthreads();
    for (int i = tid; i < cnt; i += 256) {
        unsigned it = items[i];
        int p = atomicAdd(&cur[(it >> 16) & 255], 1);
        csr_src[gb + p] = (int)(it & 0xFFFFu);
    }
}

// ---------------- fused: aggregate 16 nodes -> swizzled LDS -> MFMA ---------
// r16 structure verbatim; only change: XOR swizzle on the Alds frag-major
// write/read (swz = ((kt&3)<<3) ^ ((g&1)<<5), identical both sides; (kt+4)&3
// == kt&3 so one swz covers both heads). Write banks 16-way -> 2-way.
__global__ __launch_bounds__(256) void agg_mfma_kernel(
    const _Float16* __restrict__ xh, const float* __restrict__ a_s,
    const float* __restrict__ a_d, const int* __restrict__ row_ptr,
    const int* __restrict__ csr_src, const _Float16* __restrict__ wT,
    const float* __restrict__ bias, const float* __restrict__ vs_next,
    const float* __restrict__ vd_next, float* __restrict__ as_next,
    float* __restrict__ ad_next, float* __restrict__ outf,
    _Float16* __restrict__ outh, int n) {
    __shared__ __align__(16) _Float16 Alds[8 * 512];   // 8 KB
    __shared__ float part[4][16][4];                   // 1 KB
    int tid = threadIdx.x;
    int wave = tid >> 6, lane = tid & 63;
    int m0 = blockIdx.x * 16;
    int sub = lane >> 4, cq = lane & 15;

    // ---- phase 1: gather-aggregate 4 nodes per wave ----
    const _Float16* xb = xh + 8 * cq;
    for (int nd = 0; nd < 4; ++nd) {
        int nl = wave * 4 + nd;
        int node = m0 + nl;
        if (node >= n) break;
        int beg = row_ptr[node], end = row_ptr[node + 1];
        float2 ad = *reinterpret_cast<const float2*>(a_d + (size_t)node * 2);
        float s0 = 0.f, s1 = 0.f;
        float acc0[8] = {}, acc1[8] = {};
        for (int chunk = beg; chunk < end; chunk += 64) {
            int cnt = min(64, end - chunk);
            int j_l = 0;
            unsigned pp_l = 0;
            if (lane < cnt) {
                j_l = csr_src[chunk + lane];
                float2 as2 = *reinterpret_cast<const float2*>(a_s + (size_t)j_l * 2);
                float e0 = as2.x + ad.x; e0 = (e0 > 0.f) ? e0 : 0.2f * e0;
                float e1 = as2.y + ad.y; e1 = (e1 > 0.f) ? e1 : 0.2f * e1;
                f16x2 pq = {(_Float16)__expf(e0), (_Float16)__expf(e1)};
                pp_l = __builtin_bit_cast(unsigned, pq);
                s0 += (float)pq[0];
                s1 += (float)pq[1];
            }
#pragma unroll 4
            for (int k = 0; k < cnt; k += 4) {
                int idx = k + sub;
                unsigned ppu = (unsigned)__shfl((int)pp_l, idx, 64);
                int j = __shfl(j_l, idx, 64);
                f16x2 pq = __builtin_bit_cast(f16x2, ppu);
                float p0 = (float)pq[0], p1 = (float)pq[1];
                f16x8 hv = *reinterpret_cast<const f16x8*>(xb + (size_t)j * D);
#pragma unroll
                for (int i = 0; i < 8; ++i) {
                    float h = (float)hv[i];
                    acc0[i] += p0 * h;
                    acc1[i] += p1 * h;
                }
            }
        }
#pragma unroll
        for (int i = 0; i < 8; ++i) {
            acc0[i] += __shfl_xor(acc0[i], 16, 64);
            acc0[i] += __shfl_xor(acc0[i], 32, 64);
            acc1[i] += __shfl_xor(acc1[i], 16, 64);
            acc1[i] += __shfl_xor(acc1[i], 32, 64);
        }
#pragma unroll
        for (int off = 1; off < 64; off <<= 1) {
            s0 += __shfl_xor(s0, off, 64);
            s1 += __shfl_xor(s1, off, 64);
        }
        if (sub == 0) {
            float i0 = 1.f / s0, i1 = 1.f / s1;
            f16x8 o0, o1;
#pragma unroll
            for (int i = 0; i < 8; ++i) {
                o0[i] = (_Float16)(acc0[i] * i0);
                o1[i] = (_Float16)(acc1[i] * i1);
            }
            // frag-major + XOR swizzle (same swz on read; (kt0+4)&3 == kt0&3)
            int kt0 = cq >> 2, g0 = cq & 3;
            int swz = ((kt0 & 3) << 3) ^ ((g0 & 1) << 5);
            *reinterpret_cast<f16x8*>(Alds + ((kt0 * 512 + (g0 * 16 + nl) * 8) ^ swz))       = o0;
            *reinterpret_cast<f16x8*>(Alds + (((4 + kt0) * 512 + (g0 * 16 + nl) * 8) ^ swz)) = o1;
        }
    }
    __syncthreads();

    // ---- phase 2: MFMA, wave covers cols 32*wave .. 32*wave+31 ----
    int ml = lane & 15, g = lane >> 4;
    f32x4 accA = {}, accB = {};
    int nt0 = wave * 2, nt1 = wave * 2 + 1;
    const _Float16* b0 = wT + (size_t)(nt0 * 16 + ml) * NCOLS + 8 * g;
    const _Float16* b1 = wT + (size_t)(nt1 * 16 + ml) * NCOLS + 8 * g;
#pragma unroll
    for (int kt = 0; kt < 8; ++kt) {
        int swzr = ((kt & 3) << 3) ^ ((g & 1) << 5);
        f16x8 av = *reinterpret_cast<const f16x8*>(Alds + ((kt * 512 + lane * 8) ^ swzr));
        int ko = kt * 32;
        f16x8 bv0 = *reinterpret_cast<const f16x8*>(b0 + ko);
        f16x8 bv1 = *reinterpret_cast<const f16x8*>(b1 + ko);
        accA = __builtin_amdgcn_mfma_f32_16x16x32_f16(av, bv0, accA, 0, 0, 0);
        accB = __builtin_amdgcn_mfma_f32_16x16x32_f16(av, bv1, accB, 0, 0, 0);
    }

    int col0 = nt0 * 16 + ml, col1 = nt1 * 16 + ml;
    float bA = bias[col0], bB = bias[col1];
    float vsA0 = 0.f, vsA1 = 0.f, vdA0 = 0.f, vdA1 = 0.f;
    float vsB0 = 0.f, vsB1 = 0.f, vdB0 = 0.f, vdB1 = 0.f;
    if (vs_next) {
        vsA0 = vs_next[col0]; vsA1 = vs_next[D + col0];
        vdA0 = vd_next[col0]; vdA1 = vd_next[D + col0];
        vsB0 = vs_next[col1]; vsB1 = vs_next[D + col1];
        vdB0 = vd_next[col1]; vdB1 = vd_next[D + col1];
    }

#pragma unroll
    for (int r = 0; r < 4; ++r) {
        int lrow = g * 4 + r;
        int orow = m0 + lrow;
        float vA = accA[r] + bA;
        float vB = accB[r] + bB;
        if (orow < n) {
            if (outf) {
                outf[(size_t)orow * D + col0] = vA;
                outf[(size_t)orow * D + col1] = vB;
            }
            if (outh) {
                outh[(size_t)orow * D + col0] = (_Float16)vA;
                outh[(size_t)orow * D + col1] = (_Float16)vB;
            }
        }
        if (vs_next) {
            float ps0 = vA * vsA0 + vB * vsB0;
            float ps1 = vA * vsA1 + vB * vsB1;
            float pd0 = vA * vdA0 + vB * vdB0;
            float pd1 = vA * vdA1 + vB * vdB1;
#pragma unroll
            for (int off = 1; off < 16; off <<= 1) {
                ps0 += __shfl_xor(ps0, off, 64);
                ps1 += __shfl_xor(ps1, off, 64);
                pd0 += __shfl_xor(pd0, off, 64);
                pd1 += __shfl_xor(pd1, off, 64);
            }
            if (ml == 0) {
                part[wave][lrow][0] = ps0;
                part[wave][lrow][1] = ps1;
                part[wave][lrow][2] = pd0;
                part[wave][lrow][3] = pd1;
            }
        }
    }
    if (vs_next) {
        __syncthreads();
        if (tid < 64) {
            int row = tid >> 2, q = tid & 3;
            int node = m0 + row;
            if (node < n) {
                float v = part[0][row][q] + part[1][row][q]
                        + part[2][row][q] + part[3][row][q];
                float* dstp = (q < 2) ? as_next : ad_next;
                dstp[(size_t)node * 2 + (q & 1)] = v;
            }
        }
    }
}

// ---------------- launch ----------------
extern "C" void kernel_launch(void* const* d_in, const int* in_sizes, int n_in,
                              void* d_out, int out_size, void* d_ws, size_t ws_size,
                              hipStream_t stream) {
    const float* x    = (const float*)d_in[0];
    const void*  ei   = d_in[1];
    const float* W1   = (const float*)d_in[2];
    const float* as1v = (const float*)d_in[3];
    const float* ad1v = (const float*)d_in[4];
    const float* b1   = (const float*)d_in[5];
    const float* W2   = (const float*)d_in[6];
    const float* as2v = (const float*)d_in[7];
    const float* ad2v = (const float*)d_in[8];
    const float* b2   = (const float*)d_in[9];
    float* out = (float*)d_out;

    const int N  = in_sizes[0] / D;
    const int E  = in_sizes[1] / 2;
    const int ET = E + N;
    const int NBUCK = (N + NPB - 1) / NPB;
    const int NBB = (E + P1CHUNK - 1) / P1CHUNK;

    char* w = (char*)d_ws;
    size_t off = 0;
    auto alloc = [&](size_t bytes) {
        void* p = w + off;
        off = (off + bytes + 15) & ~(size_t)15;
        return p;
    };
    int*      flag    = (int*)     alloc(16);
    int*      gcnt    = (int*)     alloc(256 * 4);
    unsigned* bins    = (unsigned*)alloc((size_t)NBUCK * CAP * 4);
    int*      row_ptr = (int*)     alloc((size_t)(N + 1) * 4);
    int*      csr_src = (int*)     alloc((size_t)ET * 4);
    float*    v_s1    = (float*)   alloc(NCOLS * 4);
    float*    v_d1    = (float*)   alloc(NCOLS * 4);
    _Float16* wT1     = (_Float16*)alloc((size_t)NCOLS * D * 2);
    float*    v_s2    = (float*)   alloc(NCOLS * 4);
    float*    v_d2    = (float*)   alloc(NCOLS * 4);
    _Float16* wT2     = (_Float16*)alloc((size_t)NCOLS * D * 2);
    float*    a_s1    = (float*)   alloc((size_t)N * 2 * 4);
    float*    a_d1    = (float*)   alloc((size_t)N * 2 * 4);
    float*    a_s2    = (float*)   alloc((size_t)N * 2 * 4);
    float*    a_d2    = (float*)   alloc((size_t)N * 2 * 4);
    _Float16* xh      = (_Float16*)alloc((size_t)N * D * 2);
    _Float16* xmh     = (_Float16*)alloc((size_t)N * D * 2);

    // 1) weight prep + detect/gcnt-zero
    hipLaunchKernelGGL(attprep_kernel, dim3(35), dim3(256), 0, stream,
                       W1, as1v, ad1v, v_s1, v_d1, wT1,
                       W2, as2v, ad2v, v_s2, v_d2, wT2, ei, flag, gcnt);
    // 2) bin (blocks 0..NBB-1) + prep_x (rest)
    hipLaunchKernelGGL(binprep_kernel, dim3(NBB + (N + 3) / 4), dim3(256), 0, stream,
                       ei, flag, bins, gcnt, E, NBUCK,
                       x, v_s1, v_d1, xh, a_s1, a_d1, N, NBB);
    // 3) per-bucket CSR build
    hipLaunchKernelGGL(build_kernel, dim3(NBUCK), dim3(256), 0, stream,
                       bins, gcnt, row_ptr, csr_src, N, NBUCK);
    // 4) layer 1 fused (emits xmh + layer-2 a_s/a_d)
    hipLaunchKernelGGL(agg_mfma_kernel, dim3((N + 15) / 16), dim3(256), 0, stream,
                       xh, a_s1, a_d1, row_ptr, csr_src, wT1, b1,
                       v_s2, v_d2, a_s2, a_d2, (float*)nullptr, xmh, N);
    // 5) layer 2 fused (emits out)
    hipLaunchKernelGGL(agg_mfma_kernel, dim3((N + 15) / 16), dim3(256), 0, stream,
                       xmh, a_s2, a_d2, row_ptr, csr_src, wT2, b2,
                       (const float*)nullptr, (const float*)nullptr,
                       (float*)nullptr, (float*)nullptr, out, (_Float16*)nullptr, N);
}